// Round 4
// baseline (119.066 us; speedup 1.0000x reference)
//
#include <hip/hip_runtime.h>
#include <hip/hip_cooperative_groups.h>
#include <stdint.h>
#include <string.h>
#include <math.h>

namespace cg = cooperative_groups;

// RandomGate: output depends ONLY on jax.random.key(42) and dim=32768.
// Exact replication of JAX partitionable threefry streams (verified: absmax
// 0.0 rounds 2-3). This round: fuse gate + reduce into ONE cooperative
// kernel (grid.sync) to drop a graph node — 16.6us was launch-dominated.

#define DIM    32768
#define NCHAIN 48   // poisson Knuth subkey chain depth; P(need>48) ~ 0
#define BLOCKS 1024 // DIM*8/256 threads, one per (row, j); 4 blocks/CU

struct P1 {
  uint32_t kr0, kr1;            // k_rand
  uint32_t km0, km1;            // k_mult
  uint32_t sub0[NCHAIN];        // poisson subkey chain (host-precomputed)
  uint32_t sub1[NCHAIN];
  float    invp[8];             // 1/p_k  (argmin w*invp == argmax logp+gumbel)
};
struct P2 { int invperm[8]; };  // inverse of jax.random.permutation(k_perm, 8)

__host__ __device__ static inline void tf2x32(uint32_t k0, uint32_t k1,
                                              uint32_t x0, uint32_t x1,
                                              uint32_t &o0, uint32_t &o1) {
  const uint32_t ks2 = 0x1BD11BDAu ^ k0 ^ k1;
  x0 += k0; x1 += k1;
#define RL(v,s) (((v) << (s)) | ((v) >> (32 - (s))))
#define RND(r) { x0 += x1; x1 = RL(x1, r); x1 ^= x0; }
  RND(13) RND(15) RND(26) RND(6)
  x0 += k1;  x1 += ks2 + 1u;
  RND(17) RND(29) RND(16) RND(24)
  x0 += ks2; x1 += k0 + 2u;
  RND(13) RND(15) RND(26) RND(6)
  x0 += k0;  x1 += k1 + 3u;
  RND(17) RND(29) RND(16) RND(24)
  x0 += k1;  x1 += ks2 + 4u;
  RND(13) RND(15) RND(26) RND(6)
  x0 += ks2; x1 += k0 + 5u;
#undef RND
#undef RL
  o0 = x0; o1 = x1;
}

// partitionable random_bits(key, 32, shape): element e -> xor of output pair
__device__ static inline uint32_t rbits(uint32_t k0, uint32_t k1, uint32_t e) {
  uint32_t o0, o1;
  tf2x32(k0, k1, 0u, e, o0, o1);
  return o0 ^ o1;
}

__device__ static inline float u01(uint32_t bits) {
  return __uint_as_float((bits >> 9) | 0x3F800000u) - 1.0f;  // [0, 1)
}

__global__ void __launch_bounds__(256, 4)
fused_kernel(P1 P, P2 Q, int* __restrict__ ws, int* __restrict__ out) {
  __shared__ int hist[8];
  if (threadIdx.x < 8) hist[threadIdx.x] = 0;
  __syncthreads();

  const uint32_t gid  = blockIdx.x * 256u + threadIdx.x;  // (row, j) flat
  const uint32_t row8 = gid & ~7u;                        // row * 8
  const int      j    = (int)(gid & 7u);
  const float TINY = 1.17549435e-38f;

  // ---- categorical: argmax_k (gumbel + logp_k) == argmin_k (-log u_k)/p_k ----
  int bestk = 0; float best = 3.0e38f;
#pragma unroll
  for (int kk = 0; kk < 8; ++kk) {
    float f = u01(rbits(P.km0, P.km1, gid * 8u + (uint32_t)kk));
    float u = fmaxf(f, TINY);            // uniform(minval=tiny)
    float w = -__logf(u);                // > 0
    float v = w * P.invp[kk];
    if (v < best) { best = v; bestk = kk; }
  }

  // ---- rate = random_matrix[row][bestk] (take_along_axis) ----
  float lam = u01(rbits(P.kr0, P.kr1, row8 + (uint32_t)bestk));

  // ---- poisson (Knuth): count iters while log_prod > -lam; result = cnt-1 ----
  int pvi = 0;
  if (lam > 0.0f) {
    float lp = 0.0f; int kcnt = 0;
#pragma unroll 1
    for (int t = 0; t < NCHAIN; ++t) {
      if (!(lp > -lam)) break;
      ++kcnt;
      lp += __logf(u01(rbits(P.sub0[t], P.sub1[t], gid)));  // log(0)=-inf stops
    }
    pvi = kcnt - 1;                      // in [0, 47]
  }

  // ---- combine the row's 8 lanes: logits.at[row, bk_j].set(pv_j), last j
  //      wins; then argmax with first-occurrence tie-break ----
  uint32_t packed = (uint32_t)bestk | ((uint32_t)pvi << 3);   // 9 bits
  int v = 0;                              // logits start at 0
#pragma unroll
  for (int jp = 0; jp < 8; ++jp) {
    uint32_t pk = __shfl(packed, jp, 8);
    v = ((int)(pk & 7u) == j) ? (int)(pk >> 3) : v;
  }
  int am = j;
#pragma unroll
  for (int m = 1; m < 8; m <<= 1) {
    int ov = __shfl_xor(v,  m, 8);
    int oa = __shfl_xor(am, m, 8);
    if (ov > v || (ov == v && oa < am)) { v = ov; am = oa; }
  }
  if (j == 0) atomicAdd(&hist[am], 1);

  __syncthreads();
  if (threadIdx.x < 8) ws[blockIdx.x * 8 + threadIdx.x] = hist[threadIdx.x];
  __threadfence();                        // device-scope: cross-XCD visibility

  cg::this_grid().sync();

  // ---- phase 2: block 0 reduces 1024x8 partials, permuted store ----
  if (blockIdx.x == 0) {
    __shared__ int part[256];
    const int t = threadIdx.x;
    const int col = t & 7, chunk = t >> 3;   // 32 chunks x 32 block-rows
    int s = 0;
#pragma unroll
    for (int r = 0; r < 32; ++r) s += ws[(chunk * 32 + r) * 8 + col];
    part[t] = s;
    __syncthreads();
    if (t < 8) {
      int tot = 0;
#pragma unroll
      for (int c = 0; c < 32; ++c) tot += part[c * 8 + t];
      out[Q.invperm[t]] = tot;             // plain store, also zero-inits
    }
  }
}

extern "C" void kernel_launch(void* const* d_in, const int* in_sizes, int n_in,
                              void* d_out, int out_size, void* d_ws, size_t ws_size,
                              hipStream_t stream) {
  (void)d_in; (void)in_sizes; (void)n_in; (void)ws_size; (void)out_size;

  P1 P; P2 Q;

  // ---- key(42) = (0,42) -> split(key,4): child i = pair of TF(key, 0, i) ----
  uint32_t c0[4], c1[4];
  for (uint32_t i = 0; i < 4; ++i)
    tf2x32(0u, 42u, 0u, i, c0[i], c1[i]);
  P.kr0 = c0[0]; P.kr1 = c1[0];          // k_rand
  P.km0 = c0[1]; P.km1 = c1[1];          // k_mult
  uint32_t kp0 = c0[2], kp1 = c1[2];     // k_pois
  uint32_t kq0 = c0[3], kq1 = c1[3];     // k_perm

  // ---- poisson Knuth subkey chain: rng=TF(rng,0,0), sub=TF(rng,0,1) ----
  {
    uint32_t r0 = kp0, r1 = kp1;
    for (int t = 0; t < NCHAIN; ++t) {
      uint32_t n0, n1, s0, s1;
      tf2x32(r0, r1, 0u, 0u, n0, n1);
      tf2x32(r0, r1, 0u, 1u, s0, s1);
      P.sub0[t] = s0; P.sub1[t] = s1;
      r0 = n0; r1 = n1;
    }
  }

  // ---- permutation(k_perm, 8): argsort of random_bits(subkey, 32, (8,)) ----
  {
    uint32_t s0, s1;
    tf2x32(kq0, kq1, 0u, 1u, s0, s1);    // _, subkey = split(k_perm)
    uint32_t sk[8];
    for (uint32_t i = 0; i < 8; ++i) {
      uint32_t a, b;
      tf2x32(s0, s1, 0u, i, a, b);
      sk[i] = a ^ b;
    }
    int perm[8]; bool used[8] = {false,false,false,false,false,false,false,false};
    for (int pos = 0; pos < 8; ++pos) {  // stable argsort ascending
      int best = -1;
      for (int i = 0; i < 8; ++i) {
        if (used[i]) continue;
        if (best < 0 || sk[i] < sk[best]) best = i;
      }
      used[best] = true; perm[pos] = best;
    }
    for (int i = 0; i < 8; ++i) Q.invperm[perm[i]] = i;
  }

  // ---- invp: 1 / softmax(power-law), f32 mirroring the reference ----
  {
    float exps[8], Z = 0.0f;
    for (int e = 0; e < 8; ++e) { exps[e] = powf((float)(e + 1), -3.0f); Z += exps[e]; }
    for (int e = 0; e < 8; ++e) P.invp[e] = Z / exps[e];
  }

  int* out = (int*)d_out;
  int* ws  = (int*)d_ws;   // BLOCKS*8 ints = 32 KB
  void* args[] = { &P, &Q, &ws, &out };
  hipLaunchCooperativeKernel(reinterpret_cast<void*>(fused_kernel),
                             dim3(BLOCKS), dim3(256), args, 0, stream);
}

// Round 5
// 18.230 us; speedup vs baseline: 6.5314x; 6.5314x over previous
//
#include <hip/hip_runtime.h>
#include <stdint.h>
#include <string.h>
#include <math.h>

// RandomGate: output depends ONLY on jax.random.key(42) and dim=32768.
// Exact replication of JAX partitionable threefry streams (absmax 0.0 in
// rounds 2-4). Round 4 lesson: cooperative grid.sync costs ~90us — reverted.
// This round: ONE kernel node, no grid barrier. Block 0 reduces after
// polling per-block MAGIC flags. Safe because the kernel is deterministic
// and input-independent: partials in ws are bit-identical every call, so a
// stale MAGIC from a previous call yields identical partial values anyway.
// Agent-scope atomics handle cross-XCD L2 non-coherence (guide G16).

#define DIM    32768
#define NCHAIN 48          // poisson Knuth chain depth; P(need>48) ~ 0
#define BLOCKS 1024        // one thread per (row, j)
#define MAGIC  0x5F3A9C71u // != 0, != 0xAAAAAAAA poison

struct P1 {
  uint32_t kr0, kr1;            // k_rand
  uint32_t km0, km1;            // k_mult
  uint32_t sub0[NCHAIN];        // poisson subkey chain (host-precomputed)
  uint32_t sub1[NCHAIN];
  float    invp[8];             // 1/p_k (argmin w*invp == argmax logp+gumbel)
};
struct P2 { int invperm[8]; };  // inverse of jax.random.permutation(k_perm, 8)

__host__ __device__ static inline void tf2x32(uint32_t k0, uint32_t k1,
                                              uint32_t x0, uint32_t x1,
                                              uint32_t &o0, uint32_t &o1) {
  const uint32_t ks2 = 0x1BD11BDAu ^ k0 ^ k1;
  x0 += k0; x1 += k1;
#define RL(v,s) (((v) << (s)) | ((v) >> (32 - (s))))
#define RND(r) { x0 += x1; x1 = RL(x1, r); x1 ^= x0; }
  RND(13) RND(15) RND(26) RND(6)
  x0 += k1;  x1 += ks2 + 1u;
  RND(17) RND(29) RND(16) RND(24)
  x0 += ks2; x1 += k0 + 2u;
  RND(13) RND(15) RND(26) RND(6)
  x0 += k0;  x1 += k1 + 3u;
  RND(17) RND(29) RND(16) RND(24)
  x0 += k1;  x1 += ks2 + 4u;
  RND(13) RND(15) RND(26) RND(6)
  x0 += ks2; x1 += k0 + 5u;
#undef RND
#undef RL
  o0 = x0; o1 = x1;
}

// partitionable random_bits(key, 32, shape): element e -> xor of output pair
__device__ static inline uint32_t rbits(uint32_t k0, uint32_t k1, uint32_t e) {
  uint32_t o0, o1;
  tf2x32(k0, k1, 0u, e, o0, o1);
  return o0 ^ o1;
}

__device__ static inline float u01(uint32_t bits) {
  return __uint_as_float((bits >> 9) | 0x3F800000u) - 1.0f;  // [0, 1)
}

__global__ void __launch_bounds__(256, 4)
fused_kernel(P1 P, P2 Q, int* __restrict__ ws, int* __restrict__ out) {
  __shared__ int hist[8];
  if (threadIdx.x < 8) hist[threadIdx.x] = 0;
  __syncthreads();

  const uint32_t gid  = blockIdx.x * 256u + threadIdx.x;  // (row, j) flat
  const uint32_t row8 = gid & ~7u;                        // row * 8
  const int      j    = (int)(gid & 7u);
  const float TINY = 1.17549435e-38f;

  // ---- categorical: argmax_k (gumbel + logp_k) == argmin_k (-log u_k)/p_k ----
  int bestk = 0; float best = 3.0e38f;
#pragma unroll
  for (int kk = 0; kk < 8; ++kk) {
    float f = u01(rbits(P.km0, P.km1, gid * 8u + (uint32_t)kk));
    float u = fmaxf(f, TINY);            // uniform(minval=tiny)
    float w = -__logf(u);                // > 0
    float v = w * P.invp[kk];
    if (v < best) { best = v; bestk = kk; }
  }

  // ---- rate = random_matrix[row][bestk] (take_along_axis) ----
  float lam = u01(rbits(P.kr0, P.kr1, row8 + (uint32_t)bestk));

  // ---- poisson (Knuth): count iters while log_prod > -lam; result = cnt-1 ----
  int pvi = 0;
  if (lam > 0.0f) {
    float lp = 0.0f; int kcnt = 0;
#pragma unroll 1
    for (int t = 0; t < NCHAIN; ++t) {
      if (!(lp > -lam)) break;
      ++kcnt;
      lp += __logf(u01(rbits(P.sub0[t], P.sub1[t], gid)));  // log(0)=-inf stops
    }
    pvi = kcnt - 1;                      // in [0, 47]
  }

  // ---- combine row's 8 lanes: logits.at[row, bk_j].set(pv_j), last j wins;
  //      argmax with first-occurrence tie-break (softmax is monotone) ----
  uint32_t packed = (uint32_t)bestk | ((uint32_t)pvi << 3);   // 9 bits
  int v = 0;                              // logits start at 0
#pragma unroll
  for (int jp = 0; jp < 8; ++jp) {
    uint32_t pk = __shfl(packed, jp, 8);
    v = ((int)(pk & 7u) == j) ? (int)(pk >> 3) : v;
  }
  int am = j;
#pragma unroll
  for (int m = 1; m < 8; m <<= 1) {
    int ov = __shfl_xor(v,  m, 8);
    int oa = __shfl_xor(am, m, 8);
    if (ov > v || (ov == v && oa < am)) { v = ov; am = oa; }
  }
  if (j == 0) atomicAdd(&hist[am], 1);
  __syncthreads();

  int*      partials = ws;                          // [8][BLOCKS] transposed
  uint32_t* flags    = (uint32_t*)(ws + 8 * BLOCKS);// [BLOCKS]

  // thread 0 stores all 8 partials then release-stores the flag: single-thread
  // program order + release gives agent-scope visibility ordering.
  if (threadIdx.x == 0) {
#pragma unroll
    for (int e = 0; e < 8; ++e)
      __hip_atomic_store(&partials[e * BLOCKS + blockIdx.x], hist[e],
                         __ATOMIC_RELAXED, __HIP_MEMORY_SCOPE_AGENT);
    __hip_atomic_store(&flags[blockIdx.x], MAGIC,
                       __ATOMIC_RELEASE, __HIP_MEMORY_SCOPE_AGENT);
  }

  // ---- block 0: poll all flags, then reduce 8x1024 partials, permuted store.
  //      Stale MAGIC from a prior call is benign: partials are value-identical
  //      across calls (deterministic, input-independent kernel). ----
  if (blockIdx.x == 0) {
    const int t = threadIdx.x;
    for (;;) {
      bool done = true;
#pragma unroll
      for (int q = 0; q < 4; ++q) {
        uint32_t f = __hip_atomic_load(&flags[t + q * 256],
                                       __ATOMIC_RELAXED, __HIP_MEMORY_SCOPE_AGENT);
        done &= (f == MAGIC);
      }
      if (__syncthreads_and((int)done)) break;
      __builtin_amdgcn_s_sleep(2);
    }
    __threadfence();  // acquire side

    const int e = t >> 5, l = t & 31;   // expert e, lane l: coalesced columns
    int s = 0;
#pragma unroll
    for (int r = 0; r < 32; ++r)
      s += __hip_atomic_load(&partials[e * BLOCKS + l + 32 * r],
                             __ATOMIC_RELAXED, __HIP_MEMORY_SCOPE_AGENT);
    __shared__ int part[256];
    part[t] = s;
    __syncthreads();
    if (t < 8) {
      int tot = 0;
#pragma unroll
      for (int c = 0; c < 32; ++c) tot += part[t * 32 + c];
      out[Q.invperm[t]] = tot;           // full rewrite each call (poison-safe)
    }
  }
}

extern "C" void kernel_launch(void* const* d_in, const int* in_sizes, int n_in,
                              void* d_out, int out_size, void* d_ws, size_t ws_size,
                              hipStream_t stream) {
  (void)d_in; (void)in_sizes; (void)n_in; (void)ws_size; (void)out_size;

  P1 P; P2 Q;

  // ---- key(42) = (0,42) -> split(key,4): child i = pair of TF(key, 0, i) ----
  uint32_t c0[4], c1[4];
  for (uint32_t i = 0; i < 4; ++i)
    tf2x32(0u, 42u, 0u, i, c0[i], c1[i]);
  P.kr0 = c0[0]; P.kr1 = c1[0];          // k_rand
  P.km0 = c0[1]; P.km1 = c1[1];          // k_mult
  uint32_t kp0 = c0[2], kp1 = c1[2];     // k_pois
  uint32_t kq0 = c0[3], kq1 = c1[3];     // k_perm

  // ---- poisson Knuth subkey chain: rng=TF(rng,0,0), sub=TF(rng,0,1) ----
  {
    uint32_t r0 = kp0, r1 = kp1;
    for (int t = 0; t < NCHAIN; ++t) {
      uint32_t n0, n1, s0, s1;
      tf2x32(r0, r1, 0u, 0u, n0, n1);
      tf2x32(r0, r1, 0u, 1u, s0, s1);
      P.sub0[t] = s0; P.sub1[t] = s1;
      r0 = n0; r1 = n1;
    }
  }

  // ---- permutation(k_perm, 8): argsort of random_bits(subkey, 32, (8,)) ----
  {
    uint32_t s0, s1;
    tf2x32(kq0, kq1, 0u, 1u, s0, s1);    // _, subkey = split(k_perm)
    uint32_t sk[8];
    for (uint32_t i = 0; i < 8; ++i) {
      uint32_t a, b;
      tf2x32(s0, s1, 0u, i, a, b);
      sk[i] = a ^ b;
    }
    int perm[8]; bool used[8] = {false,false,false,false,false,false,false,false};
    for (int pos = 0; pos < 8; ++pos) {  // stable argsort ascending
      int best = -1;
      for (int i = 0; i < 8; ++i) {
        if (used[i]) continue;
        if (best < 0 || sk[i] < sk[best]) best = i;
      }
      used[best] = true; perm[pos] = best;
    }
    for (int i = 0; i < 8; ++i) Q.invperm[perm[i]] = i;
  }

  // ---- invp: 1 / softmax(power-law), f32 mirroring the reference ----
  {
    float exps[8], Z = 0.0f;
    for (int e = 0; e < 8; ++e) { exps[e] = powf((float)(e + 1), -3.0f); Z += exps[e]; }
    for (int e = 0; e < 8; ++e) P.invp[e] = Z / exps[e];
  }

  int* out = (int*)d_out;
  int* ws  = (int*)d_ws;   // 8*BLOCKS partials + BLOCKS flags = 36 KB
  fused_kernel<<<BLOCKS, 256, 0, stream>>>(P, Q, ws, out);
}

// Round 7
// 16.901 us; speedup vs baseline: 7.0448x; 1.0786x over previous
//
#include <hip/hip_runtime.h>
#include <stdint.h>
#include <string.h>
#include <math.h>

// RandomGate: output depends ONLY on jax.random.key(42) and dim=32768.
// Exact replication of JAX partitionable threefry streams (absmax 0.0,
// rounds 2-5). Structure: two graph nodes (gate -> reduce), the measured
// optimum (coop grid.sync +100us r4; single-node flag-poll +1.6us r5;
// host-side compute -> harness timeout r6). This round: per-block histogram
// (8 bins, each <=32) packed into ONE uint64 -> ws 32KB->8KB, 1-store gate
// epilogue, wave-butterfly reduce.

#define DIM    32768
#define NCHAIN 48   // poisson Knuth chain depth; P(need>48) ~ 0
#define BLOCKS 1024 // one thread per (row, j); 32 rows per block

struct P1 {
  uint32_t kr0, kr1;            // k_rand
  uint32_t km0, km1;            // k_mult
  uint32_t sub0[NCHAIN];        // poisson subkey chain (host-precomputed)
  uint32_t sub1[NCHAIN];
  float    invp[8];             // 1/p_k (argmin w*invp == argmax logp+gumbel)
};
struct P2 { int invperm[8]; };  // inverse of jax.random.permutation(k_perm, 8)

__host__ __device__ static inline void tf2x32(uint32_t k0, uint32_t k1,
                                              uint32_t x0, uint32_t x1,
                                              uint32_t &o0, uint32_t &o1) {
  const uint32_t ks2 = 0x1BD11BDAu ^ k0 ^ k1;
  x0 += k0; x1 += k1;
#define RL(v,s) (((v) << (s)) | ((v) >> (32 - (s))))
#define RND(r) { x0 += x1; x1 = RL(x1, r); x1 ^= x0; }
  RND(13) RND(15) RND(26) RND(6)
  x0 += k1;  x1 += ks2 + 1u;
  RND(17) RND(29) RND(16) RND(24)
  x0 += ks2; x1 += k0 + 2u;
  RND(13) RND(15) RND(26) RND(6)
  x0 += k0;  x1 += k1 + 3u;
  RND(17) RND(29) RND(16) RND(24)
  x0 += k1;  x1 += ks2 + 4u;
  RND(13) RND(15) RND(26) RND(6)
  x0 += ks2; x1 += k0 + 5u;
#undef RND
#undef RL
  o0 = x0; o1 = x1;
}

// partitionable random_bits(key, 32, shape): element e -> xor of output pair
__device__ static inline uint32_t rbits(uint32_t k0, uint32_t k1, uint32_t e) {
  uint32_t o0, o1;
  tf2x32(k0, k1, 0u, e, o0, o1);
  return o0 ^ o1;
}

__device__ static inline float u01(uint32_t bits) {
  return __uint_as_float((bits >> 9) | 0x3F800000u) - 1.0f;  // [0, 1)
}

__global__ void __launch_bounds__(256, 4)
gate_kernel(P1 P, unsigned long long* __restrict__ ws) {
  __shared__ int hist[8];
  if (threadIdx.x < 8) hist[threadIdx.x] = 0;
  __syncthreads();

  const uint32_t gid  = blockIdx.x * 256u + threadIdx.x;  // (row, j) flat
  const uint32_t row8 = gid & ~7u;                        // row * 8
  const int      j    = (int)(gid & 7u);
  const float TINY = 1.17549435e-38f;

  // ---- categorical: argmax_k (gumbel + logp_k) == argmin_k (-log u_k)/p_k ----
  int bestk = 0; float best = 3.0e38f;
#pragma unroll
  for (int kk = 0; kk < 8; ++kk) {
    float f = u01(rbits(P.km0, P.km1, gid * 8u + (uint32_t)kk));
    float u = fmaxf(f, TINY);            // uniform(minval=tiny)
    float w = -__logf(u);                // > 0
    float v = w * P.invp[kk];
    if (v < best) { best = v; bestk = kk; }
  }

  // ---- rate = random_matrix[row][bestk] (take_along_axis) ----
  float lam = u01(rbits(P.kr0, P.kr1, row8 + (uint32_t)bestk));

  // ---- poisson (Knuth): count iters while log_prod > -lam; result = cnt-1 ----
  int pvi = 0;
  if (lam > 0.0f) {
    float lp = 0.0f; int kcnt = 0;
#pragma unroll 1
    for (int t = 0; t < NCHAIN; ++t) {
      if (!(lp > -lam)) break;
      ++kcnt;
      lp += __logf(u01(rbits(P.sub0[t], P.sub1[t], gid)));  // log(0)=-inf stops
    }
    pvi = kcnt - 1;                      // in [0, 47]
  }

  // ---- combine row's 8 lanes: logits.at[row, bk_j].set(pv_j), last j wins;
  //      argmax with first-occurrence tie-break (softmax is monotone) ----
  uint32_t packed = (uint32_t)bestk | ((uint32_t)pvi << 3);   // 9 bits
  int v = 0;                              // logits start at 0
#pragma unroll
  for (int jp = 0; jp < 8; ++jp) {
    uint32_t pk = __shfl(packed, jp, 8);
    v = ((int)(pk & 7u) == j) ? (int)(pk >> 3) : v;
  }
  int am = j;
#pragma unroll
  for (int m = 1; m < 8; m <<= 1) {
    int ov = __shfl_xor(v,  m, 8);
    int oa = __shfl_xor(am, m, 8);
    if (ov > v || (ov == v && oa < am)) { v = ov; am = oa; }
  }
  if (j == 0) atomicAdd(&hist[am], 1);
  __syncthreads();

  // ---- pack the block's 8 counts (each <= 32 rows) into one u64 ----
  if (threadIdx.x == 0) {
    unsigned long long pk = 0ull;
#pragma unroll
    for (int e = 0; e < 8; ++e)
      pk |= (unsigned long long)(uint32_t)hist[e] << (8 * e);
    ws[blockIdx.x] = pk;
  }
}

__global__ void __launch_bounds__(256)
reduce_kernel(P2 P, const unsigned long long* __restrict__ ws,
              int* __restrict__ out) {
  const int t = threadIdx.x;

  // 4 coalesced u64 loads/thread; byte-extract into 8 static-indexed regs
  int s0=0,s1=0,s2=0,s3=0,s4=0,s5=0,s6=0,s7=0;
#pragma unroll
  for (int r = 0; r < 4; ++r) {
    unsigned long long v = ws[t + 256 * r];
    s0 += (int)((v      ) & 0xFFull);
    s1 += (int)((v >>  8) & 0xFFull);
    s2 += (int)((v >> 16) & 0xFFull);
    s3 += (int)((v >> 24) & 0xFFull);
    s4 += (int)((v >> 32) & 0xFFull);
    s5 += (int)((v >> 40) & 0xFFull);
    s6 += (int)((v >> 48) & 0xFFull);
    s7 += (int)((v >> 56) & 0xFFull);
  }
  // wave butterfly (64 lanes)
#pragma unroll
  for (int m = 1; m < 64; m <<= 1) {
    s0 += __shfl_xor(s0, m); s1 += __shfl_xor(s1, m);
    s2 += __shfl_xor(s2, m); s3 += __shfl_xor(s3, m);
    s4 += __shfl_xor(s4, m); s5 += __shfl_xor(s5, m);
    s6 += __shfl_xor(s6, m); s7 += __shfl_xor(s7, m);
  }
  // cross-wave combine: lane 0 of each of the 4 waves -> LDS[wave][8]
  __shared__ int part[4][8];
  if ((t & 63) == 0) {
    const int w = t >> 6;
    part[w][0]=s0; part[w][1]=s1; part[w][2]=s2; part[w][3]=s3;
    part[w][4]=s4; part[w][5]=s5; part[w][6]=s6; part[w][7]=s7;
  }
  __syncthreads();
  if (t < 8) {
    int tot = part[0][t] + part[1][t] + part[2][t] + part[3][t];
    out[P.invperm[t]] = tot;             // full rewrite each call (poison-safe)
  }
}

extern "C" void kernel_launch(void* const* d_in, const int* in_sizes, int n_in,
                              void* d_out, int out_size, void* d_ws, size_t ws_size,
                              hipStream_t stream) {
  (void)d_in; (void)in_sizes; (void)n_in; (void)ws_size; (void)out_size;

  P1 P; P2 Q;

  // ---- key(42) = (0,42) -> split(key,4): child i = pair of TF(key, 0, i) ----
  uint32_t c0[4], c1[4];
  for (uint32_t i = 0; i < 4; ++i)
    tf2x32(0u, 42u, 0u, i, c0[i], c1[i]);
  P.kr0 = c0[0]; P.kr1 = c1[0];          // k_rand
  P.km0 = c0[1]; P.km1 = c1[1];          // k_mult
  uint32_t kp0 = c0[2], kp1 = c1[2];     // k_pois
  uint32_t kq0 = c0[3], kq1 = c1[3];     // k_perm

  // ---- poisson Knuth subkey chain: rng=TF(rng,0,0), sub=TF(rng,0,1) ----
  {
    uint32_t r0 = kp0, r1 = kp1;
    for (int t = 0; t < NCHAIN; ++t) {
      uint32_t n0, n1, s0, s1;
      tf2x32(r0, r1, 0u, 0u, n0, n1);
      tf2x32(r0, r1, 0u, 1u, s0, s1);
      P.sub0[t] = s0; P.sub1[t] = s1;
      r0 = n0; r1 = n1;
    }
  }

  // ---- permutation(k_perm, 8): argsort of random_bits(subkey, 32, (8,)) ----
  {
    uint32_t s0, s1;
    tf2x32(kq0, kq1, 0u, 1u, s0, s1);    // _, subkey = split(k_perm)
    uint32_t sk[8];
    for (uint32_t i = 0; i < 8; ++i) {
      uint32_t a, b;
      tf2x32(s0, s1, 0u, i, a, b);
      sk[i] = a ^ b;
    }
    int perm[8]; bool used[8] = {false,false,false,false,false,false,false,false};
    for (int pos = 0; pos < 8; ++pos) {  // stable argsort ascending
      int best = -1;
      for (int i = 0; i < 8; ++i) {
        if (used[i]) continue;
        if (best < 0 || sk[i] < sk[best]) best = i;
      }
      used[best] = true; perm[pos] = best;
    }
    for (int i = 0; i < 8; ++i) Q.invperm[perm[i]] = i;
  }

  // ---- invp: 1 / softmax(power-law), f32 mirroring the reference ----
  {
    float exps[8], Z = 0.0f;
    for (int e = 0; e < 8; ++e) { exps[e] = powf((float)(e + 1), -3.0f); Z += exps[e]; }
    for (int e = 0; e < 8; ++e) P.invp[e] = Z / exps[e];
  }

  int* out = (int*)d_out;
  unsigned long long* ws = (unsigned long long*)d_ws;  // BLOCKS u64 = 8 KB
  gate_kernel<<<BLOCKS, 256, 0, stream>>>(P, ws);
  reduce_kernel<<<1, 256, 0, stream>>>(Q, ws, out);
}